// Round 1
// baseline (708.688 us; speedup 1.0000x reference)
//
#include <hip/hip_runtime.h>

// Shapes: S=128, I=J=512, CM=256, C=D=32, CZ=128. Output [1,512,512,128] fp32.
#define EPS 1e-5f

typedef _Float16 half8 __attribute__((ext_vector_type(8)));
typedef _Float16 half4 __attribute__((ext_vector_type(4)));
typedef float f32x4 __attribute__((ext_vector_type(4)));

// a/b workspace layout: [2 k-chunks][16384 (i*32+c) rows][72 halves] ; cols 0..63 = s_loc, 64..71 pad
// 72-half row (144 B): 16B-aligned rows, dword stride 36 -> 4m%32 start banks -> 2-way (free).
#define AB_STRIDE 72
#define AB_CHUNK  (16384 * AB_STRIDE)

__device__ __forceinline__ void load16_to_lds(const void* g, void* l) {
    __builtin_amdgcn_global_load_lds((__attribute__((address_space(1))) void*)g,
                                     (__attribute__((address_space(3))) void*)l, 16, 0, 0);
}

// ---------------- Kernel 1: LayerNorm + A/B projection (MFMA), transposed-chunked store ---------
// 1024 blocks x 256 threads; each block: 64 rows (one s, 64 consecutive i).
__global__ __launch_bounds__(256, 2)
void k1_ln_proj(const float* __restrict__ x, const float* __restrict__ nw,
                const float* __restrict__ nb, const float* __restrict__ Wa,
                const float* __restrict__ Wb, _Float16* __restrict__ aT,
                _Float16* __restrict__ bT)
{
    // stride 264 halves: 16B-aligned rows, dword stride 132 -> 4m%32 -> 2-way (free)
    __shared__ _Float16 xln[64 * 264];
    __shared__ _Float16 Wld[64 * 264];   // rows 0..31 = Wa, 32..63 = Wb

    const int tid  = threadIdx.x;
    const int lane = tid & 63;
    const int w    = tid >> 6;
    const int quad = lane >> 4;
    const int l15  = lane & 15;

    // stage Wa/Wb -> LDS fp16 (coalesced over m)
    for (int e = tid; e < 64 * 256; e += 256) {
        int r = e >> 8, m = e & 255;
        float v = (r < 32) ? Wa[r * 256 + m] : Wb[(r - 32) * 256 + m];
        Wld[r * 264 + m] = (_Float16)v;
    }

    const int row_base = blockIdx.x * 64;
    // LN: each wave normalizes its own 16 rows into xln
    for (int rr = 0; rr < 16; ++rr) {
        int row_loc = w * 16 + rr;
        const float4* xr = (const float4*)(x + (size_t)(row_base + row_loc) * 256);
        float4 v = xr[lane];
        float sum = v.x + v.y + v.z + v.w;
        float ss  = v.x * v.x + v.y * v.y + v.z * v.z + v.w * v.w;
        #pragma unroll
        for (int off = 32; off > 0; off >>= 1) {
            sum += __shfl_xor(sum, off);
            ss  += __shfl_xor(ss, off);
        }
        float mu  = sum * (1.f / 256.f);
        float var = ss * (1.f / 256.f) - mu * mu;
        float rs  = rsqrtf(var + EPS);
        float4 gw = ((const float4*)nw)[lane];
        float4 gb = ((const float4*)nb)[lane];
        half4 o;
        o[0] = (_Float16)((v.x - mu) * rs * gw.x + gb.x);
        o[1] = (_Float16)((v.y - mu) * rs * gw.y + gb.y);
        o[2] = (_Float16)((v.z - mu) * rs * gw.z + gb.z);
        o[3] = (_Float16)((v.w - mu) * rs * gw.w + gb.w);
        *(half4*)(xln + row_loc * 264 + lane * 4) = o;
    }
    __syncthreads();

    // GEMM: each wave M=16 (its rows) x N=64 x K=256
    f32x4 acc[4] = {};
    #pragma unroll
    for (int kk = 0; kk < 8; ++kk) {
        half8 af = *(const half8*)(xln + (w * 16 + l15) * 264 + kk * 32 + quad * 8);
        #pragma unroll
        for (int nt = 0; nt < 4; ++nt) {
            half8 bf = *(const half8*)(Wld + (nt * 16 + l15) * 264 + kk * 32 + quad * 8);
            acc[nt] = __builtin_amdgcn_mfma_f32_16x16x32_f16(af, bf, acc[nt], 0, 0, 0);
        }
    }

    // scatter-store fp16 results into transposed chunked layout
    const int s_glob = row_base >> 9;      // uniform per block
    const int ck     = s_glob >> 6;
    const int s_loc  = s_glob & 63;
    const int i_base = row_base & 511;
    #pragma unroll
    for (int nt = 0; nt < 4; ++nt) {
        int c64 = nt * 16 + l15;                       // 0..63 ; <32 -> a, else b (wave-uniform per nt)
        _Float16* dst = (c64 < 32) ? aT : bT;
        int cc = c64 & 31;
        #pragma unroll
        for (int r = 0; r < 4; ++r) {
            int row_loc = w * 16 + quad * 4 + r;
            int i_ = i_base + row_loc;
            dst[(size_t)ck * AB_CHUNK + (size_t)(i_ * 32 + cc) * AB_STRIDE + s_loc] = (_Float16)acc[nt][r];
        }
    }
}

// ---------------- Kernel: Wo fp32 -> fp16 ----------------
__global__ void k_wo_cvt(const float* __restrict__ Wo, _Float16* __restrict__ WoH)
{
    int idx = (blockIdx.x * 256 + threadIdx.x) * 4;    // 128 blocks cover 131072
    float4 v = *(const float4*)(Wo + idx);
    half4 h;
    h[0] = (_Float16)v.x; h[1] = (_Float16)v.y; h[2] = (_Float16)v.z; h[3] = (_Float16)v.w;
    *(half4*)(WoH + idx) = h;
}

// ---------------- Kernel 2: fused outer-product-mean + Wo projection ----------------
// grid (128 j-tiles, 128 i-tiles) x 256 threads. Per block: 4 i x 4 j.
// Phase 1: O[(ic),(jd)] 128x128 over K=S=128 (two K=64 staged chunks).
// Phase 2: Z[pair=16][k=128] = O_tile[16][1024] @ Wo^T, O via LDS layout transform.
__global__ __launch_bounds__(256, 2)
void k2_main(const _Float16* __restrict__ aT, const _Float16* __restrict__ bT,
             const _Float16* __restrict__ WoH, const float* __restrict__ bo,
             float* __restrict__ out)
{
    __shared__ _Float16 smem[2 * 128 * AB_STRIDE];     // 36864 B: sA | sB ; o_lds overlaps after
    _Float16* sA = smem;
    _Float16* sB = smem + 128 * AB_STRIDE;

    const int tid  = threadIdx.x;
    const int lane = tid & 63;
    const int w    = tid >> 6;
    const int quad = lane >> 4;
    const int l15  = lane & 15;
    const int wy   = w >> 1, wx = w & 1;

    const int jt = blockIdx.x, it = blockIdx.y;
    const _Float16* gsrc = (w < 2) ? (aT + (size_t)it * 128 * AB_STRIDE)
                                   : (bT + (size_t)jt * 128 * AB_STRIDE);
    _Float16* ldst  = (w < 2) ? sA : sB;
    const int half_ = w & 1;

    f32x4 acc[4][4] = {};

    for (int ck = 0; ck < 2; ++ck) {
        // stage one K=64 chunk: 18432 B/slab, 2 waves/slab, 9 x 1024 B per wave, width-16 DMA
        const char* g = (const char*)(gsrc + (size_t)ck * AB_CHUNK);
        #pragma unroll
        for (int itr = 0; itr < 9; ++itr) {
            int off = itr * 2048 + half_ * 1024;
            load16_to_lds(g + off + lane * 16, (char*)ldst + off);
        }
        __syncthreads();

        #pragma unroll
        for (int kloc = 0; kloc < 2; ++kloc) {
            half8 af[4], bf[4];
            #pragma unroll
            for (int mt = 0; mt < 4; ++mt)
                af[mt] = *(const half8*)(sA + (wy * 64 + mt * 16 + l15) * AB_STRIDE + kloc * 32 + quad * 8);
            #pragma unroll
            for (int nt = 0; nt < 4; ++nt)
                bf[nt] = *(const half8*)(sB + (wx * 64 + nt * 16 + l15) * AB_STRIDE + kloc * 32 + quad * 8);
            #pragma unroll
            for (int mt = 0; mt < 4; ++mt)
                #pragma unroll
                for (int nt = 0; nt < 4; ++nt)
                    acc[mt][nt] = __builtin_amdgcn_mfma_f32_16x16x32_f16(af[mt], bf[nt], acc[mt][nt], 0, 0, 0);
        }
        __syncthreads();   // also protects sA/sB reuse (next chunk / o_lds)
    }

    // C/D layout -> A-operand layout via LDS: o_lds[pair=il*4+jl][cd=c*32+d], stride 1032
    // (dword stride 516 -> 4m%32 start banks -> 2-way, free; 16B-aligned rows)
    _Float16* oL = smem;   // 16*1032 = 16512 halves <= 18432 available
    #pragma unroll
    for (int mt = 0; mt < 4; ++mt) {
        #pragma unroll
        for (int nt = 0; nt < 4; ++nt) {
            int n  = wx * 64 + nt * 16 + l15;
            int jl = n >> 5, d = n & 31;
            #pragma unroll
            for (int r = 0; r < 4; ++r) {
                int m  = wy * 64 + mt * 16 + quad * 4 + r;
                int il = m >> 5, c = m & 31;
                oL[(il * 4 + jl) * 1032 + c * 32 + d] = (_Float16)(acc[mt][nt][r] * (1.f / 128.f));
            }
        }
    }
    __syncthreads();

    // Phase 2: each wave N=32 columns (k_out in [w*32, w*32+32)), M=16, K=1024
    f32x4 zacc[2] = {};
    const int n0 = w * 32 + l15;
    #pragma unroll 4
    for (int kk = 0; kk < 32; ++kk) {
        half8 oa = *(const half8*)(oL + l15 * 1032 + kk * 32 + quad * 8);
        half8 w0 = *(const half8*)(WoH + (size_t)n0 * 1024 + kk * 32 + quad * 8);
        half8 w1 = *(const half8*)(WoH + (size_t)(n0 + 16) * 1024 + kk * 32 + quad * 8);
        zacc[0] = __builtin_amdgcn_mfma_f32_16x16x32_f16(oa, w0, zacc[0], 0, 0, 0);
        zacc[1] = __builtin_amdgcn_mfma_f32_16x16x32_f16(oa, w1, zacc[1], 0, 0, 0);
    }

    // epilogue: add bias, store fp32
    #pragma unroll
    for (int nt = 0; nt < 2; ++nt) {
        int n = n0 + nt * 16;
        float bias = bo[n];
        #pragma unroll
        for (int r = 0; r < 4; ++r) {
            int pair = quad * 4 + r;
            int i_ = it * 4 + (pair >> 2);
            int j_ = jt * 4 + (pair & 3);
            out[((size_t)i_ * 512 + j_) * 128 + n] = zacc[nt][r] + bias;
        }
    }
}

extern "C" void kernel_launch(void* const* d_in, const int* in_sizes, int n_in,
                              void* d_out, int out_size, void* d_ws, size_t ws_size,
                              hipStream_t stream)
{
    const float* x      = (const float*)d_in[0];
    const float* norm_w = (const float*)d_in[1];
    const float* norm_b = (const float*)d_in[2];
    const float* Wa     = (const float*)d_in[3];
    const float* Wb     = (const float*)d_in[4];
    const float* Wo     = (const float*)d_in[5];
    const float* bo     = (const float*)d_in[6];
    float* out = (float*)d_out;

    _Float16* aT  = (_Float16*)d_ws;                       // 2*16384*72 halves
    _Float16* bT  = aT + 2 * (size_t)AB_CHUNK;
    _Float16* WoH = bT + 2 * (size_t)AB_CHUNK;             // 131072 halves

    k_wo_cvt<<<128, 256, 0, stream>>>(Wo, WoH);
    k1_ln_proj<<<1024, 256, 0, stream>>>(x, norm_w, norm_b, Wa, Wb, aT, bT);
    k2_main<<<dim3(128, 128), 256, 0, stream>>>(aT, bT, WoH, bo, out);
}

// Round 2
// 484.954 us; speedup vs baseline: 1.4614x; 1.4614x over previous
//
#include <hip/hip_runtime.h>

// Shapes: S=128, I=J=512, CM=256, C=D=32, CZ=128. Output [1,512,512,128] fp32.
#define EPS 1e-5f

typedef _Float16 half8 __attribute__((ext_vector_type(8)));
typedef _Float16 half4 __attribute__((ext_vector_type(4)));
typedef float f32x4 __attribute__((ext_vector_type(4)));

// a/b workspace layout: [2 k-chunks][16384 (i*32+c) rows][72 halves]; cols 0..63 = s_loc, 64..71 pad.
#define AB_STRIDE 72
#define AB_CHUNK  (16384 * AB_STRIDE)

__device__ __forceinline__ void load16_to_lds(const void* g, void* l) {
    __builtin_amdgcn_global_load_lds((__attribute__((address_space(1))) void*)g,
                                     (__attribute__((address_space(3))) void*)l, 16, 0, 0);
}

// ---------------- cvt kernel: WoH (fp16, K permuted to k'=d*32+c) + WabH (fp16) ----------------
__global__ void k_cvt(const float* __restrict__ Wo, const float* __restrict__ Wa,
                      const float* __restrict__ Wb, _Float16* __restrict__ WoH,
                      _Float16* __restrict__ WabH)
{
    int t = blockIdx.x * 256 + threadIdx.x;     // 144 blocks -> 36864 threads
    if (t < 32768) {
        int n  = t >> 8;
        int k4 = (t & 255) * 4;                 // k = c*32 + d ; 4 consecutive d, same c
        float4 v = *(const float4*)(Wo + (size_t)n * 1024 + k4);
        int c = k4 >> 5, d0 = k4 & 31;
        _Float16* dst = WoH + (size_t)n * 1024 + c;
        dst[(d0 + 0) * 32] = (_Float16)v.x;
        dst[(d0 + 1) * 32] = (_Float16)v.y;
        dst[(d0 + 2) * 32] = (_Float16)v.z;
        dst[(d0 + 3) * 32] = (_Float16)v.w;
    } else {
        int idx = (t - 32768) * 4;              // 16384 elems: rows 0..31 Wa, 32..63 Wb
        const float* src = (idx < 8192) ? (Wa + idx) : (Wb + (idx - 8192));
        float4 v = *(const float4*)src;
        half4 h;
        h[0] = (_Float16)v.x; h[1] = (_Float16)v.y; h[2] = (_Float16)v.z; h[3] = (_Float16)v.w;
        *(half4*)(WabH + idx) = h;
    }
}

// ---------------- Kernel 1: LN + A/B projection, coalesced transposed store ----------------
// 256 blocks x 512 threads. Block: 4 i values x 64 s values (sc selects s-chunk / ck).
__global__ __launch_bounds__(512, 4)
void k1_ln_proj(const float* __restrict__ x, const float* __restrict__ nw,
                const float* __restrict__ nb, const _Float16* __restrict__ WabH,
                _Float16* __restrict__ aT, _Float16* __restrict__ bT)
{
    __shared__ _Float16 xln[64 * 264];   // 33792 B
    __shared__ _Float16 oT[256 * 72];    // 36864 B: rows 0..127 a (i_l*32+c), 128..255 b

    const int tid  = threadIdx.x;
    const int lane = tid & 63;
    const int w    = tid >> 6;
    const int quad = lane >> 4;
    const int l15  = lane & 15;
    const int i0   = (blockIdx.x >> 1) * 4;
    const int sc   = blockIdx.x & 1;

    const int mt  = w & 3;
    const int ntg = w >> 2;

    for (int sub = 0; sub < 4; ++sub) {
        // LN: 8 rows per wave; row rl = s_l16*4 + i_l
        for (int rr = 0; rr < 8; ++rr) {
            int rl = w * 8 + rr;
            int s_ = sc * 64 + sub * 16 + (rl >> 2);
            int i_ = i0 + (rl & 3);
            const float4* xr = (const float4*)(x + ((size_t)s_ * 512 + i_) * 256);
            float4 v = xr[lane];
            float sum = v.x + v.y + v.z + v.w;
            float ss  = v.x * v.x + v.y * v.y + v.z * v.z + v.w * v.w;
            #pragma unroll
            for (int off = 32; off > 0; off >>= 1) {
                sum += __shfl_xor(sum, off);
                ss  += __shfl_xor(ss, off);
            }
            float mu  = sum * (1.f / 256.f);
            float var = ss * (1.f / 256.f) - mu * mu;
            float rs  = rsqrtf(var + EPS);
            float4 gw = ((const float4*)nw)[lane];
            float4 gb = ((const float4*)nb)[lane];
            half4 o;
            o[0] = (_Float16)((v.x - mu) * rs * gw.x + gb.x);
            o[1] = (_Float16)((v.y - mu) * rs * gw.y + gb.y);
            o[2] = (_Float16)((v.z - mu) * rs * gw.z + gb.z);
            o[3] = (_Float16)((v.w - mu) * rs * gw.w + gb.w);
            *(half4*)(xln + rl * 264 + lane * 4) = o;
        }
        __syncthreads();

        // GEMM 64x64x256: wave -> M-tile mt, N-tiles ntg*32 + {0,16}
        f32x4 acc2[2] = {};
        #pragma unroll
        for (int kk = 0; kk < 8; ++kk) {
            half8 af = *(const half8*)(xln + (mt * 16 + l15) * 264 + kk * 32 + quad * 8);
            #pragma unroll
            for (int t = 0; t < 2; ++t) {
                half8 bf = *(const half8*)(WabH + (ntg * 32 + t * 16 + l15) * 256 + kk * 32 + quad * 8);
                acc2[t] = __builtin_amdgcn_mfma_f32_16x16x32_f16(af, bf, acc2[t], 0, 0, 0);
            }
        }

        // transform: D[m][n]: m = mt*16+quad*4+r -> s_l16 = mt*4+quad, i_l = r; n -> c64
        #pragma unroll
        for (int t = 0; t < 2; ++t) {
            int c64  = ntg * 32 + t * 16 + l15;
            int base = ((c64 >= 32) ? 128 : 0) + (c64 & 31);
            int s_l  = sub * 16 + mt * 4 + quad;
            #pragma unroll
            for (int r = 0; r < 4; ++r)
                oT[(base + r * 32) * 72 + s_l] = (_Float16)acc2[t][r];
        }
        __syncthreads();
    }

    // coalesced store: 256 rows x 64 halves (8 x 16B units per row)
    #pragma unroll
    for (int it2 = 0; it2 < 4; ++it2) {
        int u   = it2 * 512 + tid;
        int row = u >> 3;
        int off = (u & 7) * 8;
        half8 v = *(const half8*)(oT + row * 72 + off);
        _Float16* dst = (row < 128) ? aT : bT;
        int grow = i0 * 32 + (row & 127);
        *(half8*)(dst + (size_t)sc * AB_CHUNK + (size_t)grow * 72 + off) = v;
    }
}

// ---------------- Kernel 2: fused outer-product-mean + Wo projection ----------------
// grid (jt=128, it=64) x 512 threads. Per block: 8 i x 4 j.
__global__ __launch_bounds__(512, 4)
void k2_main(const _Float16* __restrict__ aT, const _Float16* __restrict__ bT,
             const _Float16* __restrict__ WoH, const float* __restrict__ bo,
             float* __restrict__ out)
{
    __shared__ _Float16 smem[33024];               // 66048 B
    _Float16* sA = smem;                           // 256 rows x 72
    _Float16* sB = smem + 256 * AB_STRIDE;         // 128 rows x 72
    _Float16* oL = smem;                           // 32 pairs x 1032 (overlaps after phase 1)

    const int tid  = threadIdx.x;
    const int lane = tid & 63;
    const int w    = tid >> 6;
    const int quad = lane >> 4;
    const int l15  = lane & 15;
    const int wy   = w >> 1, wx = w & 1;

    const int jt = blockIdx.x, it = blockIdx.y;
    const char* gA = (const char*)(aT + (size_t)it * 256 * AB_STRIDE);
    const char* gB = (const char*)(bT + (size_t)jt * 128 * AB_STRIDE);

    f32x4 acc[4][4] = {};

    for (int ck = 0; ck < 2; ++ck) {
        // stage: sA 36 segs + sB 18 segs of 1024 B
        const char* cA = gA + (size_t)ck * (AB_CHUNK * 2);
        const char* cB = gB + (size_t)ck * (AB_CHUNK * 2);
        for (int seg = w; seg < 54; seg += 8) {
            if (seg < 36) load16_to_lds(cA + seg * 1024 + lane * 16, (char*)sA + seg * 1024 + lane * 16);
            else          load16_to_lds(cB + (seg - 36) * 1024 + lane * 16, (char*)sB + (seg - 36) * 1024 + lane * 16);
        }
        __syncthreads();

        #pragma unroll
        for (int kloc = 0; kloc < 2; ++kloc) {
            half8 af[4], bf[4];
            #pragma unroll
            for (int mt = 0; mt < 4; ++mt)
                af[mt] = *(const half8*)(sA + (wy * 64 + mt * 16 + l15) * AB_STRIDE + kloc * 32 + quad * 8);
            #pragma unroll
            for (int nt = 0; nt < 4; ++nt)
                bf[nt] = *(const half8*)(sB + (wx * 64 + nt * 16 + l15) * AB_STRIDE + kloc * 32 + quad * 8);
            #pragma unroll
            for (int mt = 0; mt < 4; ++mt)
                #pragma unroll
                for (int nt = 0; nt < 4; ++nt)
                    acc[mt][nt] = __builtin_amdgcn_mfma_f32_16x16x32_f16(af[mt], bf[nt], acc[mt][nt], 0, 0, 0);
        }
        __syncthreads();
    }

    // C/D -> A-operand transform into oL[pair][k'=d*32+c], XOR-swizzled 16B chunks.
    // m = wy*64+mt*16+quad*4+r: il = wy*2+(mt>>1), c = (mt&1)*16+quad*4+r
    // n = wx*64+nt*16+l15:      jl = wx*2+(nt>>1), d = (nt&1)*16+l15
    #pragma unroll
    for (int mt = 0; mt < 4; ++mt) {
        int c0     = (mt & 1) * 16 + quad * 4;
        int chunk3 = (c0 >> 3);                    // (mt&1)*2 + (quad>>1)
        int il     = wy * 2 + (mt >> 1);
        #pragma unroll
        for (int nt = 0; nt < 4; ++nt) {
            int d    = (nt & 1) * 16 + l15;
            int jl   = wx * 2 + (nt >> 1);
            int pair = il * 4 + jl;
            int cS   = (c0 & 7) + ((chunk3 ^ ((d >> 1) & 3)) << 3);   // swizzled c
            half4 v;
            v[0] = (_Float16)(acc[mt][nt][0] * (1.f / 128.f));
            v[1] = (_Float16)(acc[mt][nt][1] * (1.f / 128.f));
            v[2] = (_Float16)(acc[mt][nt][2] * (1.f / 128.f));
            v[3] = (_Float16)(acc[mt][nt][3] * (1.f / 128.f));
            *(half4*)(oL + pair * 1032 + d * 32 + cS) = v;
        }
    }
    __syncthreads();

    // Phase 2: wave w -> N cols [w*16, w*16+16), M = 32 pairs (2 tiles), K = 1024
    f32x4 zacc[2] = {};
    const int n0 = w * 16 + l15;
    #pragma unroll 4
    for (int kk = 0; kk < 32; ++kk) {
        int csw = (quad ^ ((kk >> 1) & 3)) * 8;    // un-swizzle chunk
        half8 oa0 = *(const half8*)(oL + (l15) * 1032 + kk * 32 + csw);
        half8 oa1 = *(const half8*)(oL + (16 + l15) * 1032 + kk * 32 + csw);
        half8 w0  = *(const half8*)(WoH + (size_t)n0 * 1024 + kk * 32 + quad * 8);
        zacc[0] = __builtin_amdgcn_mfma_f32_16x16x32_f16(oa0, w0, zacc[0], 0, 0, 0);
        zacc[1] = __builtin_amdgcn_mfma_f32_16x16x32_f16(oa1, w0, zacc[1], 0, 0, 0);
    }

    // epilogue: pair = mt2*16+quad*4+r -> il = mt2*4+quad, jl = r ; n = w*16+l15
    float bias = bo[w * 16 + l15];
    #pragma unroll
    for (int mt2 = 0; mt2 < 2; ++mt2) {
        #pragma unroll
        for (int r = 0; r < 4; ++r) {
            int il = mt2 * 4 + quad;
            int jl = r;
            out[(((size_t)(it * 8 + il)) * 512 + jt * 4 + jl) * 128 + w * 16 + l15] = zacc[mt2][r] + bias;
        }
    }
}

extern "C" void kernel_launch(void* const* d_in, const int* in_sizes, int n_in,
                              void* d_out, int out_size, void* d_ws, size_t ws_size,
                              hipStream_t stream)
{
    const float* x      = (const float*)d_in[0];
    const float* norm_w = (const float*)d_in[1];
    const float* norm_b = (const float*)d_in[2];
    const float* Wa     = (const float*)d_in[3];
    const float* Wb     = (const float*)d_in[4];
    const float* Wo     = (const float*)d_in[5];
    const float* bo     = (const float*)d_in[6];
    float* out = (float*)d_out;

    _Float16* aT   = (_Float16*)d_ws;                      // 2*16384*72
    _Float16* bT   = aT + 2 * (size_t)AB_CHUNK;
    _Float16* WoH  = bT + 2 * (size_t)AB_CHUNK;            // 131072
    _Float16* WabH = WoH + 131072;                         // 16384

    k_cvt<<<144, 256, 0, stream>>>(Wo, Wa, Wb, WoH, WabH);
    k1_ln_proj<<<256, 512, 0, stream>>>(x, norm_w, norm_b, WabH, aT, bT);
    k2_main<<<dim3(128, 64), 512, 0, stream>>>(aT, bT, WoH, bo, out);
}